// Round 2
// baseline (186.996 us; speedup 1.0000x reference)
//
#include <hip/hip_runtime.h>

// ---------------------------------------------------------------------------
// StandardMultiHeadAttention: B=2, S=2048, D=1024, H=16, Dh=64, causal.
// fp32->f16 convert (single kernel) -> QKV GEMM (BK=64, frag-major epilogue)
// -> flash attention (S^T tiles, static-base softmax) -> output GEMM (BK=64,
// 128x64 tiles, direct fp32 write + bias).
//
// Workspace (48 MB):
//   [0,8M)    xb : x f16 [4096,1024]
//   [8M,16M)  wb : Wq,Wk,Wv,Wo f16 (row=out, K-major)
//   [16M,24M) QF : Q frag-major (pre-scaled by 0.125*log2e)
//   [24M,32M) KF : K frag-major
//   [32M,40M) VF : V^T frag-major
//   [40M,48M) ob : attention output [B,S,1024] f16
//
// R14 == R13 resubmit (R13 bench was an infra failure: container failed
// twice, no counters). R13: attn restructured barrier-free. Old: 4-wave
// split-K (t == w mod 4) per 32-row q-tile + LDS merge (2 syncthreads +
// single-wave merge per phase). New: each wave owns a 16-row q-half (roles
// {63-p,h0},{63-p,h1},{p,h0},{p,h1}, XOR-mixed across blocks so each SIMD
// gets 2 long + 2 short waves), iterates its full KV range. No __syncthreads
// anywhere. Halved per-wave state (qf 16, oacc 16, sacc 8 regs) frees room
// for a 1-tile K register prefetch under the 128-reg/wave cap (R7's spill is
// gone) -> K-load latency off the serial chain. Twin waves (h=0/1, same
// q-tile, same CU) issue identical K/V loads -> L1 absorbs the duplication.
// ---------------------------------------------------------------------------

typedef _Float16 f16x8 __attribute__((ext_vector_type(8)));
typedef _Float16 f16x4 __attribute__((ext_vector_type(4)));
typedef _Float16 f16x2 __attribute__((ext_vector_type(2)));
typedef float f32x4 __attribute__((ext_vector_type(4)));

#define S_  2048
#define DM  1024
#define NH  16
#define DH  64

__device__ __forceinline__ void gload_lds16(const void* g, void* s) {
  __builtin_amdgcn_global_load_lds(
      (const __attribute__((address_space(1))) void*)g,
      (__attribute__((address_space(3))) void*)s, 16, 0, 0);
}

__device__ __forceinline__ f16x2 pkrtz(float a, float b) {
  return __builtin_bit_cast(f16x2, __builtin_amdgcn_cvt_pkrtz(a, b));
}

// ----------------------------- convert kernel ------------------------------
// blocks [0,4096): x -> xb ; blocks [4096,8192): Wq..Wo -> wb

__global__ void cvt_all_kernel(const float* __restrict__ x,
                               const float* __restrict__ w0,
                               const float* __restrict__ w1,
                               const float* __restrict__ w2,
                               const float* __restrict__ w3,
                               _Float16* __restrict__ xb,
                               _Float16* __restrict__ wb) {
  const int bid = blockIdx.x;
  const float* src;
  _Float16* dst;
  int idx;
  if (bid < 4096) {
    src = x; dst = xb; idx = bid * 256 + threadIdx.x;
  } else {
    const int j = bid - 4096;
    const int y = j >> 10;
    src = (y == 0) ? w0 : (y == 1) ? w1 : (y == 2) ? w2 : w3;
    dst = wb + (size_t)y * (DM * DM);
    idx = (j & 1023) * 256 + threadIdx.x;
  }
  const float4 v = ((const float4*)src)[idx];
  f16x4 h;
  h[0] = (_Float16)v.x; h[1] = (_Float16)v.y;
  h[2] = (_Float16)v.z; h[3] = (_Float16)v.w;
  ((f16x4*)dst)[idx] = h;
}

// ------------------------- QKV GEMM (BK=64, 2 slabs) ------------------------
// z=0: Q (bias, *0.125*log2e, QF layout); z=1: K (KF); z=2: V (VF)

__global__ __launch_bounds__(256, 2) void gemm_qkv_kernel(
    const _Float16* __restrict__ xb, const _Float16* __restrict__ wb,
    const float* __restrict__ bq, const float* __restrict__ bk,
    const float* __restrict__ bv, _Float16* __restrict__ qkv)
{
  __shared__ _Float16 As[2][128 * 32];   // slab h: k in [k0+32h, k0+32h+32)
  __shared__ _Float16 Ws[2][128 * 32];
  const int z = blockIdx.z;
  const _Float16* W = wb + (size_t)z * (DM * DM);
  const float* bias = (z == 0) ? bq : ((z == 1) ? bk : bv);
  _Float16* out = qkv + (size_t)z * 4194304;

  const f32x4 z4 = {0.f, 0.f, 0.f, 0.f};
  f32x4 acc[4][4];
#pragma unroll
  for (int mi = 0; mi < 4; ++mi)
#pragma unroll
    for (int ni = 0; ni < 4; ++ni) acc[mi][ni] = z4;

  const int m0 = blockIdx.y * 128, n0 = blockIdx.x * 128;
  const int t = threadIdx.x;
  const int w = t >> 6, l = t & 63;
  const int quad = l >> 4, ln = l & 15;
  const int wm = (w >> 1) << 6, wn = (w & 1) << 6;
  const int srow = l >> 2, scol = (l & 3) << 3;

  for (int k0 = 0; k0 < DM; k0 += 64) {
#pragma unroll
    for (int h = 0; h < 2; ++h)
#pragma unroll
      for (int i = 0; i < 2; ++i) {
        const int ra = w * 32 + i * 16;
        gload_lds16(&xb[(size_t)(m0 + ra + srow) * DM + k0 + h * 32 + scol],
                    &As[h][ra * 32]);
        gload_lds16(&W[(size_t)(n0 + ra + srow) * DM + k0 + h * 32 + scol],
                    &Ws[h][ra * 32]);
      }
    __syncthreads();

#pragma unroll
    for (int h = 0; h < 2; ++h) {
      f16x8 af[4], bf[4];
#pragma unroll
      for (int mi = 0; mi < 4; ++mi)
        af[mi] = *(const f16x8*)&As[h][(wm + mi * 16 + ln) * 32 + quad * 8];
#pragma unroll
      for (int ni = 0; ni < 4; ++ni)
        bf[ni] = *(const f16x8*)&Ws[h][(wn + ni * 16 + ln) * 32 + quad * 8];
#pragma unroll
      for (int mi = 0; mi < 4; ++mi)
#pragma unroll
        for (int ni = 0; ni < 4; ++ni)
          acc[mi][ni] = __builtin_amdgcn_mfma_f32_16x16x32_f16(
              af[mi], bf[ni], acc[mi][ni], 0, 0, 0);
    }
    __syncthreads();
  }

  // fold 1/sqrt(Dh) * log2(e) into Q so attention uses exp2
  const float scale = (z == 0) ? 0.18033688f : 1.0f;

#pragma unroll
  for (int ni = 0; ni < 4; ++ni) {
    const int c = n0 + wn + ni * 16 + ln;
    const float bias_c = bias[c];
    const int h = c >> 6, d = c & 63;
#pragma unroll
    for (int mi = 0; mi < 4; ++mi) {
      const int mb = m0 + wm + mi * 16 + quad * 4;
#pragma unroll
      for (int r = 0; r < 4; ++r) {
        const int mg = mb + r;
        const int b = mg >> 11, s = mg & 2047;
        const int bh = b * NH + h;
        const float v = (acc[mi][ni][r] + bias_c) * scale;
        size_t idx;
        if (z == 2)
          idx = (size_t)bh * 131072 + (s >> 5) * 2048 + (d >> 4) * 512 +
                ((s >> 3) & 3) * 128 + (d & 15) * 8 + (s & 7);
        else
          idx = (size_t)bh * 131072 + (s >> 4) * 1024 + (d >> 5) * 512 +
                ((d >> 3) & 3) * 128 + (s & 15) * 8 + (d & 7);
        out[idx] = (_Float16)v;
      }
    }
  }
}

// ------------- output GEMM (BK=64 two-slab, 128x64 tile, direct) ------------

__global__ __launch_bounds__(256, 2) void gemm_out_kernel(
    const _Float16* __restrict__ ob, const _Float16* __restrict__ wo,
    const float* __restrict__ bo, float* __restrict__ out)
{
  __shared__ _Float16 As[2][128 * 32];
  __shared__ _Float16 Ws[2][64 * 32];
  const f32x4 z4 = {0.f, 0.f, 0.f, 0.f};
  f32x4 acc[2][4];
#pragma unroll
  for (int mi = 0; mi < 2; ++mi)
#pragma unroll
    for (int ni = 0; ni < 4; ++ni) acc[mi][ni] = z4;

  const int m0 = blockIdx.y * 128, n0 = blockIdx.x * 64;
  const int t = threadIdx.x;
  const int w = t >> 6, l = t & 63;
  const int quad = l >> 4, ln = l & 15;
  const int srow = l >> 2, scol = (l & 3) << 3;

  for (int k0 = 0; k0 < DM; k0 += 64) {
#pragma unroll
    for (int h = 0; h < 2; ++h) {
#pragma unroll
      for (int i = 0; i < 2; ++i) {
        const int ra = w * 32 + i * 16;
        gload_lds16(&ob[(size_t)(m0 + ra + srow) * DM + k0 + h * 32 + scol],
                    &As[h][ra * 32]);
      }
      gload_lds16(&wo[(size_t)(n0 + w * 16 + srow) * DM + k0 + h * 32 + scol],
                  &Ws[h][w * 16 * 32]);
    }
    __syncthreads();

#pragma unroll
    for (int h = 0; h < 2; ++h) {
      f16x8 af[2], bf[4];
#pragma unroll
      for (int mi = 0; mi < 2; ++mi)
        af[mi] = *(const f16x8*)&As[h][(w * 32 + mi * 16 + ln) * 32 + quad * 8];
#pragma unroll
      for (int ni = 0; ni < 4; ++ni)
        bf[ni] = *(const f16x8*)&Ws[h][(ni * 16 + ln) * 32 + quad * 8];
#pragma unroll
      for (int mi = 0; mi < 2; ++mi)
#pragma unroll
        for (int ni = 0; ni < 4; ++ni)
          acc[mi][ni] = __builtin_amdgcn_mfma_f32_16x16x32_f16(
              af[mi], bf[ni], acc[mi][ni], 0, 0, 0);
    }
    __syncthreads();
  }

#pragma unroll
  for (int ni = 0; ni < 4; ++ni) {
    const int c = n0 + ni * 16 + ln;
    const float bias_c = bo[c];
#pragma unroll
    for (int mi = 0; mi < 2; ++mi) {
      const int mb = m0 + w * 32 + mi * 16 + quad * 4;
#pragma unroll
      for (int r = 0; r < 4; ++r)
        out[(size_t)(mb + r) * DM + c] = acc[mi][ni][r] + bias_c;
    }
  }
}

// ---------------------------- flash attention ------------------------------
// R13 structure: 1024 blocks x 4 waves = 256 CU x 4 blocks exactly
// co-resident at launch_bounds(256,4). Block = (head bh, pair p). Wave role
// (XOR-mixed with i>>8 for per-SIMD long/short balance):
//   role 0/1 -> q-tile 63-p, half h=0/1 ; role 2/3 -> q-tile p, half h=0/1.
// Each wave owns 16 q-rows, iterates kv tiles 0..qw with a 1-tile K register
// prefetch (fits: qf 16 + kc 16 + kn 16 + vf 16 + oacc 16 + sacc 8 ~= 115
// regs < 128). No __syncthreads, no merge. Twin waves (h=0/1) share K/V
// loads via L1.

template <bool DIAG>
__device__ __forceinline__ void tile16(
    const _Float16* __restrict__ vb_, int t,
    const f16x8 (&kc)[4], const f16x8 (&qf)[2],
    f32x4 (&oacc)[4], float& l_i,
    _Float16* Ps, int quad, int ln, int l, int h)
{
  f16x8 vf[4];
#pragma unroll
  for (int i = 0; i < 4; ++i)
    vf[i] = *(const f16x8*)(vb_ + (size_t)(t * 4 + i) * 512 + l * 8);

  const f32x4 z4 = {0.f, 0.f, 0.f, 0.f};
  f32x4 sacc[2];
  sacc[0] = z4; sacc[1] = z4;

#pragma unroll
  for (int ks = 0; ks < 2; ++ks)
#pragma unroll
    for (int mi = 0; mi < 2; ++mi)
      sacc[mi] = __builtin_amdgcn_mfma_f32_16x16x32_f16(
          kc[mi * 2 + ks], qf[ks], sacc[mi], 0, 0, 0);

  const int sw = (ln & 3) << 1;
  float rs = 0.f;
#pragma unroll
  for (int mi = 0; mi < 2; ++mi) {
    float p[4];
#pragma unroll
    for (int r = 0; r < 4; ++r) {
      p[r] = __builtin_amdgcn_exp2f(sacc[mi][r]);
      if (DIAG && (mi * 16 + quad * 4 + r > h * 16 + ln)) p[r] = 0.f;
      rs += p[r];
    }
    const f16x2 lo = pkrtz(p[0], p[1]);
    const f16x2 hi = pkrtz(p[2], p[3]);
    const f16x4 pk = __builtin_shufflevector(lo, hi, 0, 1, 2, 3);
    const int g = (mi * 4 + quad) ^ sw;
    *(f16x4*)&Ps[ln * 40 + g * 4] = pk;
  }
  l_i += rs;

  const int g2 = (quad * 2) ^ sw;
  const f16x8 pb = *(const f16x8*)&Ps[ln * 40 + g2 * 4];

#pragma unroll
  for (int di = 0; di < 4; ++di)
    oacc[di] = __builtin_amdgcn_mfma_f32_16x16x32_f16(
        vf[di], pb, oacc[di], 0, 0, 0);
}

__global__ __launch_bounds__(256, 4) void attn_kernel(
    const _Float16* __restrict__ QF, const _Float16* __restrict__ KF,
    const _Float16* __restrict__ VF, _Float16* __restrict__ Ob)
{
  __shared__ _Float16 Ps[4 * 16 * 40];

  const int i = blockIdx.x;
  const int bh = ((i & 7) << 2) | ((i >> 3) & 3);
  const int p = i >> 5;

  const int tid = threadIdx.x;
  const int w = tid >> 6, l = tid & 63;
  const int quad = l >> 4, ln = l & 15;

  // role mixing: CU's 4 resident blocks differ in i>>8 -> every SIMD gets
  // both long (63-p) and short (p) waves regardless of dispatch mapping.
  const int role = (w + (i >> 8)) & 3;
  const int qw = (role < 2) ? (63 - p) : p;
  const int h = role & 1;

  const _Float16* qb_ = QF + (size_t)bh * 131072;
  const _Float16* kb_ = KF + (size_t)bh * 131072;
  const _Float16* vb_ = VF + (size_t)bh * 131072;
  _Float16* psw = Ps + w * (16 * 40);
  const int bidx = bh >> 4, hh = bh & 15;

  // Q fragments for rows [qw*32 + h*16, +16)
  f16x8 qf[2];
#pragma unroll
  for (int ks = 0; ks < 2; ++ks)
    qf[ks] = *(const f16x8*)
        (qb_ + (size_t)((qw * 2 + h) * 2 + ks) * 512 + l * 8);

  const f32x4 z4 = {0.f, 0.f, 0.f, 0.f};
  f32x4 oacc[4];
#pragma unroll
  for (int di = 0; di < 4; ++di) oacc[di] = z4;
  float l_i = 0.f;

  // K prefetch pipeline: kc = current tile, kn = next tile.
  f16x8 kc[4];
#pragma unroll
  for (int ii = 0; ii < 4; ++ii)
    kc[ii] = *(const f16x8*)(kb_ + (size_t)ii * 512 + l * 8);

  for (int t = 0; t < qw; ++t) {
    f16x8 kn[4];
#pragma unroll
    for (int ii = 0; ii < 4; ++ii)
      kn[ii] = *(const f16x8*)
          (kb_ + (size_t)((t + 1) * 4 + ii) * 512 + l * 8);
    tile16<false>(vb_, t, kc, qf, oacc, l_i, psw, quad, ln, l, h);
#pragma unroll
    for (int ii = 0; ii < 4; ++ii) kc[ii] = kn[ii];
  }
  tile16<true>(vb_, qw, kc, qf, oacc, l_i, psw, quad, ln, l, h);

  // row-sum across the 4 quads (lanes ln, ln+16, ln+32, ln+48)
  l_i += __shfl_xor(l_i, 16);
  l_i += __shfl_xor(l_i, 32);
  const float inv = 1.0f / l_i;

  const int q = qw * 32 + h * 16 + ln;
  _Float16* orow = Ob + (size_t)(bidx * S_ + q) * DM + hh * DH + quad * 4;
#pragma unroll
  for (int di = 0; di < 4; ++di) {
    f16x4 o4;
#pragma unroll
    for (int r = 0; r < 4; ++r)
      o4[r] = (_Float16)(oacc[di][r] * inv);
    *(f16x4*)(orow + di * 16) = o4;
  }
}

// ------------------------------- launcher ----------------------------------

extern "C" void kernel_launch(void* const* d_in, const int* in_sizes, int n_in,
                              void* d_out, int out_size, void* d_ws, size_t ws_size,
                              hipStream_t stream) {
  (void)in_sizes; (void)n_in; (void)out_size; (void)ws_size;
  const float* x  = (const float*)d_in[0];
  const float* Wq = (const float*)d_in[1];
  const float* bq = (const float*)d_in[2];
  const float* Wk = (const float*)d_in[3];
  const float* bk = (const float*)d_in[4];
  const float* Wv = (const float*)d_in[5];
  const float* bv = (const float*)d_in[6];
  const float* Wo = (const float*)d_in[7];
  const float* bo = (const float*)d_in[8];

  char* ws = (char*)d_ws;
  _Float16* xb  = (_Float16*)(ws);                      // 8 MB
  _Float16* wb  = (_Float16*)(ws + (8u << 20));         // 4 x 2 MB
  _Float16* qkv = (_Float16*)(ws + (16u << 20));        // QF,KF,VF 8 MB each
  _Float16* ob  = (_Float16*)(ws + (40u << 20));        // 8 MB

  cvt_all_kernel<<<dim3(8192), dim3(256), 0, stream>>>(x, Wq, Wk, Wv, Wo, xb, wb);
  gemm_qkv_kernel<<<dim3(8, 32, 3), dim3(256), 0, stream>>>(xb, wb, bq, bk, bv, qkv);
  attn_kernel<<<dim3(1024), dim3(256), 0, stream>>>(
      qkv, qkv + 4194304, qkv + 2 * 4194304, ob);
  gemm_out_kernel<<<dim3(16, 32), dim3(256), 0, stream>>>(
      ob, wb + (size_t)3 * DM * DM, bo, (float*)d_out);
}

// Round 3
// 183.196 us; speedup vs baseline: 1.0207x; 1.0207x over previous
//
#include <hip/hip_runtime.h>

// ---------------------------------------------------------------------------
// StandardMultiHeadAttention: B=2, S=2048, D=1024, H=16, Dh=64, causal.
// fp32->f16 convert (single kernel) -> QKV GEMM (BK=64, frag-major epilogue)
// -> flash attention (S^T tiles, static-base softmax) -> output GEMM (BK=64,
// 128x64 tiles, direct fp32 write + bias).
//
// Workspace (48 MB):
//   [0,8M)    xb : x f16 [4096,1024]
//   [8M,16M)  wb : Wq,Wk,Wv,Wo f16 (row=out, K-major)
//   [16M,24M) QF : Q frag-major (pre-scaled by 0.125*log2e)
//   [24M,32M) KF : K frag-major
//   [32M,40M) VF : V^T frag-major
//   [40M,48M) ob : attention output [B,S,1024] f16
//
// R15 post-mortem of R13: barrier-free per-wave attn REGRESSED (43.1us,
// MfmaUtil 15.5%, Occupancy 24.4% time-avg, LDS_BANK_CONFLICT 6.1M).
// Cause 1: wave imbalance (1..64 tiles/wave) -> short waves retire, blocks
// pinned by 64-serial-tile long waves, second half runs at ~2 waves/SIMD.
// Cause 2: Ps stride 40 halfs = 20 banks, gcd(20,32)=4 -> row-start banks
// repeat every 8 rows; (ln&3) XOR can't fix it -> 4-6 way conflicts.
// R15: (a) balanced waves: wave (h = w>>1, e = w&1) processes q-tile 63-p
// then q-tile p, kv tiles t == e (mod 2): every wave = 32.5 +- 1 tiles.
// Parity partners merge (O,l) via per-pair LDS add (2 barriers/block,
// phase-double-buffered). 16 waves/CU steady. K reg prefetch kept (~95
// regs < 128 cap @ launch_bounds(256,4)). (b) Ps stride 64 halfs (128 B:
// row drops out of bank index), slot = (rg + 2*ln) & 15 -> uniform banks
// on both the f16x4 writes and the f16x8 read.
// ---------------------------------------------------------------------------

typedef _Float16 f16x8 __attribute__((ext_vector_type(8)));
typedef _Float16 f16x4 __attribute__((ext_vector_type(4)));
typedef _Float16 f16x2 __attribute__((ext_vector_type(2)));
typedef float f32x4 __attribute__((ext_vector_type(4)));

#define S_  2048
#define DM  1024
#define NH  16
#define DH  64

__device__ __forceinline__ void gload_lds16(const void* g, void* s) {
  __builtin_amdgcn_global_load_lds(
      (const __attribute__((address_space(1))) void*)g,
      (__attribute__((address_space(3))) void*)s, 16, 0, 0);
}

__device__ __forceinline__ f16x2 pkrtz(float a, float b) {
  return __builtin_bit_cast(f16x2, __builtin_amdgcn_cvt_pkrtz(a, b));
}

// ----------------------------- convert kernel ------------------------------
// blocks [0,4096): x -> xb ; blocks [4096,8192): Wq..Wo -> wb

__global__ void cvt_all_kernel(const float* __restrict__ x,
                               const float* __restrict__ w0,
                               const float* __restrict__ w1,
                               const float* __restrict__ w2,
                               const float* __restrict__ w3,
                               _Float16* __restrict__ xb,
                               _Float16* __restrict__ wb) {
  const int bid = blockIdx.x;
  const float* src;
  _Float16* dst;
  int idx;
  if (bid < 4096) {
    src = x; dst = xb; idx = bid * 256 + threadIdx.x;
  } else {
    const int j = bid - 4096;
    const int y = j >> 10;
    src = (y == 0) ? w0 : (y == 1) ? w1 : (y == 2) ? w2 : w3;
    dst = wb + (size_t)y * (DM * DM);
    idx = (j & 1023) * 256 + threadIdx.x;
  }
  const float4 v = ((const float4*)src)[idx];
  f16x4 h;
  h[0] = (_Float16)v.x; h[1] = (_Float16)v.y;
  h[2] = (_Float16)v.z; h[3] = (_Float16)v.w;
  ((f16x4*)dst)[idx] = h;
}

// ------------------------- QKV GEMM (BK=64, 2 slabs) ------------------------
// z=0: Q (bias, *0.125*log2e, QF layout); z=1: K (KF); z=2: V (VF)

__global__ __launch_bounds__(256, 2) void gemm_qkv_kernel(
    const _Float16* __restrict__ xb, const _Float16* __restrict__ wb,
    const float* __restrict__ bq, const float* __restrict__ bk,
    const float* __restrict__ bv, _Float16* __restrict__ qkv)
{
  __shared__ _Float16 As[2][128 * 32];   // slab h: k in [k0+32h, k0+32h+32)
  __shared__ _Float16 Ws[2][128 * 32];
  const int z = blockIdx.z;
  const _Float16* W = wb + (size_t)z * (DM * DM);
  const float* bias = (z == 0) ? bq : ((z == 1) ? bk : bv);
  _Float16* out = qkv + (size_t)z * 4194304;

  const f32x4 z4 = {0.f, 0.f, 0.f, 0.f};
  f32x4 acc[4][4];
#pragma unroll
  for (int mi = 0; mi < 4; ++mi)
#pragma unroll
    for (int ni = 0; ni < 4; ++ni) acc[mi][ni] = z4;

  const int m0 = blockIdx.y * 128, n0 = blockIdx.x * 128;
  const int t = threadIdx.x;
  const int w = t >> 6, l = t & 63;
  const int quad = l >> 4, ln = l & 15;
  const int wm = (w >> 1) << 6, wn = (w & 1) << 6;
  const int srow = l >> 2, scol = (l & 3) << 3;

  for (int k0 = 0; k0 < DM; k0 += 64) {
#pragma unroll
    for (int h = 0; h < 2; ++h)
#pragma unroll
      for (int i = 0; i < 2; ++i) {
        const int ra = w * 32 + i * 16;
        gload_lds16(&xb[(size_t)(m0 + ra + srow) * DM + k0 + h * 32 + scol],
                    &As[h][ra * 32]);
        gload_lds16(&W[(size_t)(n0 + ra + srow) * DM + k0 + h * 32 + scol],
                    &Ws[h][ra * 32]);
      }
    __syncthreads();

#pragma unroll
    for (int h = 0; h < 2; ++h) {
      f16x8 af[4], bf[4];
#pragma unroll
      for (int mi = 0; mi < 4; ++mi)
        af[mi] = *(const f16x8*)&As[h][(wm + mi * 16 + ln) * 32 + quad * 8];
#pragma unroll
      for (int ni = 0; ni < 4; ++ni)
        bf[ni] = *(const f16x8*)&Ws[h][(wn + ni * 16 + ln) * 32 + quad * 8];
#pragma unroll
      for (int mi = 0; mi < 4; ++mi)
#pragma unroll
        for (int ni = 0; ni < 4; ++ni)
          acc[mi][ni] = __builtin_amdgcn_mfma_f32_16x16x32_f16(
              af[mi], bf[ni], acc[mi][ni], 0, 0, 0);
    }
    __syncthreads();
  }

  // fold 1/sqrt(Dh) * log2(e) into Q so attention uses exp2
  const float scale = (z == 0) ? 0.18033688f : 1.0f;

#pragma unroll
  for (int ni = 0; ni < 4; ++ni) {
    const int c = n0 + wn + ni * 16 + ln;
    const float bias_c = bias[c];
    const int h = c >> 6, d = c & 63;
#pragma unroll
    for (int mi = 0; mi < 4; ++mi) {
      const int mb = m0 + wm + mi * 16 + quad * 4;
#pragma unroll
      for (int r = 0; r < 4; ++r) {
        const int mg = mb + r;
        const int b = mg >> 11, s = mg & 2047;
        const int bh = b * NH + h;
        const float v = (acc[mi][ni][r] + bias_c) * scale;
        size_t idx;
        if (z == 2)
          idx = (size_t)bh * 131072 + (s >> 5) * 2048 + (d >> 4) * 512 +
                ((s >> 3) & 3) * 128 + (d & 15) * 8 + (s & 7);
        else
          idx = (size_t)bh * 131072 + (s >> 4) * 1024 + (d >> 5) * 512 +
                ((d >> 3) & 3) * 128 + (s & 15) * 8 + (d & 7);
        out[idx] = (_Float16)v;
      }
    }
  }
}

// ------------- output GEMM (BK=64 two-slab, 128x64 tile, direct) ------------

__global__ __launch_bounds__(256, 2) void gemm_out_kernel(
    const _Float16* __restrict__ ob, const _Float16* __restrict__ wo,
    const float* __restrict__ bo, float* __restrict__ out)
{
  __shared__ _Float16 As[2][128 * 32];
  __shared__ _Float16 Ws[2][64 * 32];
  const f32x4 z4 = {0.f, 0.f, 0.f, 0.f};
  f32x4 acc[2][4];
#pragma unroll
  for (int mi = 0; mi < 2; ++mi)
#pragma unroll
    for (int ni = 0; ni < 4; ++ni) acc[mi][ni] = z4;

  const int m0 = blockIdx.y * 128, n0 = blockIdx.x * 64;
  const int t = threadIdx.x;
  const int w = t >> 6, l = t & 63;
  const int quad = l >> 4, ln = l & 15;
  const int srow = l >> 2, scol = (l & 3) << 3;

  for (int k0 = 0; k0 < DM; k0 += 64) {
#pragma unroll
    for (int h = 0; h < 2; ++h) {
#pragma unroll
      for (int i = 0; i < 2; ++i) {
        const int ra = w * 32 + i * 16;
        gload_lds16(&ob[(size_t)(m0 + ra + srow) * DM + k0 + h * 32 + scol],
                    &As[h][ra * 32]);
      }
      gload_lds16(&wo[(size_t)(n0 + w * 16 + srow) * DM + k0 + h * 32 + scol],
                  &Ws[h][w * 16 * 32]);
    }
    __syncthreads();

#pragma unroll
    for (int h = 0; h < 2; ++h) {
      f16x8 af[2], bf[4];
#pragma unroll
      for (int mi = 0; mi < 2; ++mi)
        af[mi] = *(const f16x8*)&As[h][(w * 32 + mi * 16 + ln) * 32 + quad * 8];
#pragma unroll
      for (int ni = 0; ni < 4; ++ni)
        bf[ni] = *(const f16x8*)&Ws[h][(ni * 16 + ln) * 32 + quad * 8];
#pragma unroll
      for (int mi = 0; mi < 2; ++mi)
#pragma unroll
        for (int ni = 0; ni < 4; ++ni)
          acc[mi][ni] = __builtin_amdgcn_mfma_f32_16x16x32_f16(
              af[mi], bf[ni], acc[mi][ni], 0, 0, 0);
    }
    __syncthreads();
  }

#pragma unroll
  for (int ni = 0; ni < 4; ++ni) {
    const int c = n0 + ni * 16 + ln;
    const float bias_c = bo[c];
#pragma unroll
    for (int mi = 0; mi < 2; ++mi) {
      const int mb = m0 + w * 32 + mi * 16 + quad * 4;
#pragma unroll
      for (int r = 0; r < 4; ++r)
        out[(size_t)(mb + r) * DM + c] = acc[mi][ni][r] + bias_c;
    }
  }
}

// ---------------------------- flash attention ------------------------------
// R15: 1024 blocks x 4 waves, launch_bounds(256,4): all co-resident, 16
// waves/CU steady. Block = (bh, p). Wave = (h = w>>1, e = w&1): processes
// q-tile 63-p half h (kv tiles t == e mod 2), merge with parity partner,
// then q-tile p half h likewise. Every wave: 32.5 +- 1 tiles (balanced).
// Ps: stride 64 halfs (row drops out of bank index), slot = (rg+2*ln)&15.
// Merge: e==1 writes (O,l) to per-pair LDS, barrier, e==0 adds + outputs;
// phase-double-buffered (no WAR barrier needed). 2 barriers/block total.

template <bool DIAG>
__device__ __forceinline__ void tile16(
    const _Float16* __restrict__ vb_, int t,
    const f16x8 (&kc)[4], const f16x8 (&qf)[2],
    f32x4 (&oacc)[4], float& l_i,
    _Float16* Ps, int quad, int ln, int l, int h)
{
  f16x8 vf[4];
#pragma unroll
  for (int i = 0; i < 4; ++i)
    vf[i] = *(const f16x8*)(vb_ + (size_t)(t * 4 + i) * 512 + l * 8);

  const f32x4 z4 = {0.f, 0.f, 0.f, 0.f};
  f32x4 sacc[2];
  sacc[0] = z4; sacc[1] = z4;

#pragma unroll
  for (int ks = 0; ks < 2; ++ks)
#pragma unroll
    for (int mi = 0; mi < 2; ++mi)
      sacc[mi] = __builtin_amdgcn_mfma_f32_16x16x32_f16(
          kc[mi * 2 + ks], qf[ks], sacc[mi], 0, 0, 0);

  float rs = 0.f;
#pragma unroll
  for (int mi = 0; mi < 2; ++mi) {
    float p[4];
#pragma unroll
    for (int r = 0; r < 4; ++r) {
      p[r] = __builtin_amdgcn_exp2f(sacc[mi][r]);
      if (DIAG && (mi * 16 + quad * 4 + r > h * 16 + ln)) p[r] = 0.f;
      rs += p[r];
    }
    const f16x2 lo = pkrtz(p[0], p[1]);
    const f16x2 hi = pkrtz(p[2], p[3]);
    const f16x4 pk = __builtin_shufflevector(lo, hi, 0, 1, 2, 3);
    // rg = kv-row-group (0..7); slot swizzle uniform in banks (stride 64
    // halfs = 128 B: row index drops out of bank index entirely).
    const int slot = ((mi * 4 + quad) + 2 * ln) & 15;
    *(f16x4*)&Ps[ln * 64 + slot * 4] = pk;
  }
  l_i += rs;

  const int slot2 = ((quad * 2) + 2 * ln) & 15;  // even -> 16B aligned, no wrap
  const f16x8 pb = *(const f16x8*)&Ps[ln * 64 + slot2 * 4];

#pragma unroll
  for (int di = 0; di < 4; ++di)
    oacc[di] = __builtin_amdgcn_mfma_f32_16x16x32_f16(
        vf[di], pb, oacc[di], 0, 0, 0);
}

__device__ __forceinline__ void run_phase(
    const _Float16* __restrict__ qb_, const _Float16* __restrict__ kb_,
    const _Float16* __restrict__ vb_, _Float16* __restrict__ Ob,
    _Float16* psw, float* mO, float* mL,
    int qtile, int h, int e, int quad, int ln, int l,
    int bidx, int hh)
{
  // Q fragments for rows [qtile*32 + h*16, +16)
  f16x8 qf[2];
#pragma unroll
  for (int ks = 0; ks < 2; ++ks)
    qf[ks] = *(const f16x8*)
        (qb_ + (size_t)((qtile * 2 + h) * 2 + ks) * 512 + l * 8);

  const f32x4 z4 = {0.f, 0.f, 0.f, 0.f};
  f32x4 oacc[4];
#pragma unroll
  for (int di = 0; di < 4; ++di) oacc[di] = z4;
  float l_i = 0.f;

  const int a = qtile;
  int t = e;
  if (t <= a) {
    f16x8 kc[4];
#pragma unroll
    for (int ii = 0; ii < 4; ++ii)
      kc[ii] = *(const f16x8*)(kb_ + (size_t)(t * 4 + ii) * 512 + l * 8);
    while (t + 2 <= a) {
      f16x8 kn[4];
#pragma unroll
      for (int ii = 0; ii < 4; ++ii)
        kn[ii] = *(const f16x8*)
            (kb_ + (size_t)((t + 2) * 4 + ii) * 512 + l * 8);
      tile16<false>(vb_, t, kc, qf, oacc, l_i, psw, quad, ln, l, h);
#pragma unroll
      for (int ii = 0; ii < 4; ++ii) kc[ii] = kn[ii];
      t += 2;
    }
    if (t == a)
      tile16<true>(vb_, t, kc, qf, oacc, l_i, psw, quad, ln, l, h);
    else
      tile16<false>(vb_, t, kc, qf, oacc, l_i, psw, quad, ln, l, h);
  }

  // parity merge: e==1 writes, e==0 adds + outputs. di-major layout:
  // word addr di*256 + l*4 -> banks l*4%32, uniform (8 words/bank = min).
  if (e) {
#pragma unroll
    for (int di = 0; di < 4; ++di)
      *(f32x4*)&mO[di * 256 + l * 4] = oacc[di];
    mL[l] = l_i;
  }
  __syncthreads();
  if (!e) {
#pragma unroll
    for (int di = 0; di < 4; ++di)
      oacc[di] += *(const f32x4*)&mO[di * 256 + l * 4];
    l_i += mL[l];
    l_i += __shfl_xor(l_i, 16);
    l_i += __shfl_xor(l_i, 32);
    const float inv = 1.0f / l_i;

    const int q = qtile * 32 + h * 16 + ln;
    _Float16* orow = Ob + (size_t)(bidx * S_ + q) * DM + hh * DH + quad * 4;
#pragma unroll
    for (int di = 0; di < 4; ++di) {
      f16x4 o4;
#pragma unroll
      for (int r = 0; r < 4; ++r)
        o4[r] = (_Float16)(oacc[di][r] * inv);
      *(f16x4*)(orow + di * 16) = o4;
    }
  }
}

__global__ __launch_bounds__(256, 4) void attn_kernel(
    const _Float16* __restrict__ QF, const _Float16* __restrict__ KF,
    const _Float16* __restrict__ VF, _Float16* __restrict__ Ob)
{
  __shared__ _Float16 Ps[4 * 16 * 64];       // 8 KB, per-wave 2 KB
  __shared__ float mrgO[2][2][1024];         // 16 KB: [phase][pair][di*256+l*4]
  __shared__ float mrgL[2][2][64];           // 1 KB

  const int i = blockIdx.x;
  const int bh = ((i & 7) << 2) | ((i >> 3) & 3);
  const int p = i >> 5;

  const int tid = threadIdx.x;
  const int w = tid >> 6, l = tid & 63;
  const int quad = l >> 4, ln = l & 15;
  const int h = w >> 1;          // q-half (pair id)
  const int e = w & 1;           // kv parity

  const _Float16* qb_ = QF + (size_t)bh * 131072;
  const _Float16* kb_ = KF + (size_t)bh * 131072;
  const _Float16* vb_ = VF + (size_t)bh * 131072;
  _Float16* psw = Ps + w * (16 * 64);
  const int bidx = bh >> 4, hh = bh & 15;

  run_phase(qb_, kb_, vb_, Ob, psw, &mrgO[0][h][0], &mrgL[0][h][0],
            63 - p, h, e, quad, ln, l, bidx, hh);
  run_phase(qb_, kb_, vb_, Ob, psw, &mrgO[1][h][0], &mrgL[1][h][0],
            p, h, e, quad, ln, l, bidx, hh);
}

// ------------------------------- launcher ----------------------------------

extern "C" void kernel_launch(void* const* d_in, const int* in_sizes, int n_in,
                              void* d_out, int out_size, void* d_ws, size_t ws_size,
                              hipStream_t stream) {
  (void)in_sizes; (void)n_in; (void)out_size; (void)ws_size;
  const float* x  = (const float*)d_in[0];
  const float* Wq = (const float*)d_in[1];
  const float* bq = (const float*)d_in[2];
  const float* Wk = (const float*)d_in[3];
  const float* bk = (const float*)d_in[4];
  const float* Wv = (const float*)d_in[5];
  const float* bv = (const float*)d_in[6];
  const float* Wo = (const float*)d_in[7];
  const float* bo = (const float*)d_in[8];

  char* ws = (char*)d_ws;
  _Float16* xb  = (_Float16*)(ws);                      // 8 MB
  _Float16* wb  = (_Float16*)(ws + (8u << 20));         // 4 x 2 MB
  _Float16* qkv = (_Float16*)(ws + (16u << 20));        // QF,KF,VF 8 MB each
  _Float16* ob  = (_Float16*)(ws + (40u << 20));        // 8 MB

  cvt_all_kernel<<<dim3(8192), dim3(256), 0, stream>>>(x, Wq, Wk, Wv, Wo, xb, wb);
  gemm_qkv_kernel<<<dim3(8, 32, 3), dim3(256), 0, stream>>>(xb, wb, bq, bk, bv, qkv);
  attn_kernel<<<dim3(1024), dim3(256), 0, stream>>>(
      qkv, qkv + 4194304, qkv + 2 * 4194304, ob);
  gemm_out_kernel<<<dim3(16, 32), dim3(256), 0, stream>>>(
      ob, wb + (size_t)3 * DM * DM, bo, (float*)d_out);
}

// Round 4
// 182.980 us; speedup vs baseline: 1.0219x; 1.0012x over previous
//
#include <hip/hip_runtime.h>

// ---------------------------------------------------------------------------
// StandardMultiHeadAttention: B=2, S=2048, D=1024, H=16, Dh=64, causal.
// fp32->f16 convert (single kernel) -> QKV GEMM (BK=64, frag-major epilogue)
// -> flash attention (S^T tiles, static-base softmax) -> output GEMM (BK=64,
// 128x64 tiles, direct fp32 write + bias).
//
// Workspace (48 MB):
//   [0,8M)    xb : x f16 [4096,1024]
//   [8M,16M)  wb : Wq,Wk,Wv,Wo f16 (row=out, K-major)
//   [16M,24M) QF : Q frag-major (pre-scaled by 0.125*log2e)
//   [24M,32M) KF : K frag-major
//   [32M,40M) VF : V^T frag-major
//   [40M,48M) ob : attention output [B,S,1024] f16
//
// R16 post-mortem of R15: bank-conflict fix landed (6.1M -> 1.06M) but time
// unchanged (43.6us) -> conflicts were hidden under a larger stall. Counters:
// MfmaUtil 15.5, VALUBusy 32, HBM 6%, conflicts ~4% -> latency-bound. Per
// wave-tile ~95 issue cyc vs ~550 cyc serial chain -> need ~6 waves/SIMD;
// 1024 blocks give at most 4 (measured ~2.3 effective). R13/R15 tie because
// both hit the same TLP ceiling.
// R16: TLP x2. 2048 blocks (block = (bh, q-tile), longest-first), 4 waves =
// (h = w>>1: q-half, e = w&1: kv parity). Per-wave regs cut to ~64 unified:
// no K prefetch, K and V time-share one kv[4] register block (disjoint
// lifetimes). LDS 16.9KB/block -> 8 blocks/CU -> 32 waves/CU target.
// bh = i&31 puts all 64 blocks of a head on one XCD (32 = 0 mod 8): per-XCD
// KV working set 4 heads x 512KB = 2MB, L2-resident for the whole kernel.
// ---------------------------------------------------------------------------

typedef _Float16 f16x8 __attribute__((ext_vector_type(8)));
typedef _Float16 f16x4 __attribute__((ext_vector_type(4)));
typedef _Float16 f16x2 __attribute__((ext_vector_type(2)));
typedef float f32x4 __attribute__((ext_vector_type(4)));

#define S_  2048
#define DM  1024
#define NH  16
#define DH  64

__device__ __forceinline__ void gload_lds16(const void* g, void* s) {
  __builtin_amdgcn_global_load_lds(
      (const __attribute__((address_space(1))) void*)g,
      (__attribute__((address_space(3))) void*)s, 16, 0, 0);
}

__device__ __forceinline__ f16x2 pkrtz(float a, float b) {
  return __builtin_bit_cast(f16x2, __builtin_amdgcn_cvt_pkrtz(a, b));
}

// ----------------------------- convert kernel ------------------------------
// blocks [0,4096): x -> xb ; blocks [4096,8192): Wq..Wo -> wb

__global__ void cvt_all_kernel(const float* __restrict__ x,
                               const float* __restrict__ w0,
                               const float* __restrict__ w1,
                               const float* __restrict__ w2,
                               const float* __restrict__ w3,
                               _Float16* __restrict__ xb,
                               _Float16* __restrict__ wb) {
  const int bid = blockIdx.x;
  const float* src;
  _Float16* dst;
  int idx;
  if (bid < 4096) {
    src = x; dst = xb; idx = bid * 256 + threadIdx.x;
  } else {
    const int j = bid - 4096;
    const int y = j >> 10;
    src = (y == 0) ? w0 : (y == 1) ? w1 : (y == 2) ? w2 : w3;
    dst = wb + (size_t)y * (DM * DM);
    idx = (j & 1023) * 256 + threadIdx.x;
  }
  const float4 v = ((const float4*)src)[idx];
  f16x4 h;
  h[0] = (_Float16)v.x; h[1] = (_Float16)v.y;
  h[2] = (_Float16)v.z; h[3] = (_Float16)v.w;
  ((f16x4*)dst)[idx] = h;
}

// ------------------------- QKV GEMM (BK=64, 2 slabs) ------------------------
// z=0: Q (bias, *0.125*log2e, QF layout); z=1: K (KF); z=2: V (VF)

__global__ __launch_bounds__(256, 2) void gemm_qkv_kernel(
    const _Float16* __restrict__ xb, const _Float16* __restrict__ wb,
    const float* __restrict__ bq, const float* __restrict__ bk,
    const float* __restrict__ bv, _Float16* __restrict__ qkv)
{
  __shared__ _Float16 As[2][128 * 32];   // slab h: k in [k0+32h, k0+32h+32)
  __shared__ _Float16 Ws[2][128 * 32];
  const int z = blockIdx.z;
  const _Float16* W = wb + (size_t)z * (DM * DM);
  const float* bias = (z == 0) ? bq : ((z == 1) ? bk : bv);
  _Float16* out = qkv + (size_t)z * 4194304;

  const f32x4 z4 = {0.f, 0.f, 0.f, 0.f};
  f32x4 acc[4][4];
#pragma unroll
  for (int mi = 0; mi < 4; ++mi)
#pragma unroll
    for (int ni = 0; ni < 4; ++ni) acc[mi][ni] = z4;

  const int m0 = blockIdx.y * 128, n0 = blockIdx.x * 128;
  const int t = threadIdx.x;
  const int w = t >> 6, l = t & 63;
  const int quad = l >> 4, ln = l & 15;
  const int wm = (w >> 1) << 6, wn = (w & 1) << 6;
  const int srow = l >> 2, scol = (l & 3) << 3;

  for (int k0 = 0; k0 < DM; k0 += 64) {
#pragma unroll
    for (int h = 0; h < 2; ++h)
#pragma unroll
      for (int i = 0; i < 2; ++i) {
        const int ra = w * 32 + i * 16;
        gload_lds16(&xb[(size_t)(m0 + ra + srow) * DM + k0 + h * 32 + scol],
                    &As[h][ra * 32]);
        gload_lds16(&W[(size_t)(n0 + ra + srow) * DM + k0 + h * 32 + scol],
                    &Ws[h][ra * 32]);
      }
    __syncthreads();

#pragma unroll
    for (int h = 0; h < 2; ++h) {
      f16x8 af[4], bf[4];
#pragma unroll
      for (int mi = 0; mi < 4; ++mi)
        af[mi] = *(const f16x8*)&As[h][(wm + mi * 16 + ln) * 32 + quad * 8];
#pragma unroll
      for (int ni = 0; ni < 4; ++ni)
        bf[ni] = *(const f16x8*)&Ws[h][(wn + ni * 16 + ln) * 32 + quad * 8];
#pragma unroll
      for (int mi = 0; mi < 4; ++mi)
#pragma unroll
        for (int ni = 0; ni < 4; ++ni)
          acc[mi][ni] = __builtin_amdgcn_mfma_f32_16x16x32_f16(
              af[mi], bf[ni], acc[mi][ni], 0, 0, 0);
    }
    __syncthreads();
  }

  // fold 1/sqrt(Dh) * log2(e) into Q so attention uses exp2
  const float scale = (z == 0) ? 0.18033688f : 1.0f;

#pragma unroll
  for (int ni = 0; ni < 4; ++ni) {
    const int c = n0 + wn + ni * 16 + ln;
    const float bias_c = bias[c];
    const int h = c >> 6, d = c & 63;
#pragma unroll
    for (int mi = 0; mi < 4; ++mi) {
      const int mb = m0 + wm + mi * 16 + quad * 4;
#pragma unroll
      for (int r = 0; r < 4; ++r) {
        const int mg = mb + r;
        const int b = mg >> 11, s = mg & 2047;
        const int bh = b * NH + h;
        const float v = (acc[mi][ni][r] + bias_c) * scale;
        size_t idx;
        if (z == 2)
          idx = (size_t)bh * 131072 + (s >> 5) * 2048 + (d >> 4) * 512 +
                ((s >> 3) & 3) * 128 + (d & 15) * 8 + (s & 7);
        else
          idx = (size_t)bh * 131072 + (s >> 4) * 1024 + (d >> 5) * 512 +
                ((d >> 3) & 3) * 128 + (s & 15) * 8 + (d & 7);
        out[idx] = (_Float16)v;
      }
    }
  }
}

// ------------- output GEMM (BK=64 two-slab, 128x64 tile, direct) ------------

__global__ __launch_bounds__(256, 2) void gemm_out_kernel(
    const _Float16* __restrict__ ob, const _Float16* __restrict__ wo,
    const float* __restrict__ bo, float* __restrict__ out)
{
  __shared__ _Float16 As[2][128 * 32];
  __shared__ _Float16 Ws[2][64 * 32];
  const f32x4 z4 = {0.f, 0.f, 0.f, 0.f};
  f32x4 acc[2][4];
#pragma unroll
  for (int mi = 0; mi < 2; ++mi)
#pragma unroll
    for (int ni = 0; ni < 4; ++ni) acc[mi][ni] = z4;

  const int m0 = blockIdx.y * 128, n0 = blockIdx.x * 64;
  const int t = threadIdx.x;
  const int w = t >> 6, l = t & 63;
  const int quad = l >> 4, ln = l & 15;
  const int srow = l >> 2, scol = (l & 3) << 3;

  for (int k0 = 0; k0 < DM; k0 += 64) {
#pragma unroll
    for (int h = 0; h < 2; ++h) {
#pragma unroll
      for (int i = 0; i < 2; ++i) {
        const int ra = w * 32 + i * 16;
        gload_lds16(&ob[(size_t)(m0 + ra + srow) * DM + k0 + h * 32 + scol],
                    &As[h][ra * 32]);
      }
      gload_lds16(&wo[(size_t)(n0 + w * 16 + srow) * DM + k0 + h * 32 + scol],
                  &Ws[h][w * 16 * 32]);
    }
    __syncthreads();

#pragma unroll
    for (int h = 0; h < 2; ++h) {
      f16x8 af[2], bf[4];
#pragma unroll
      for (int mi = 0; mi < 2; ++mi)
        af[mi] = *(const f16x8*)&As[h][(w * 32 + mi * 16 + ln) * 32 + quad * 8];
#pragma unroll
      for (int ni = 0; ni < 4; ++ni)
        bf[ni] = *(const f16x8*)&Ws[h][(ni * 16 + ln) * 32 + quad * 8];
#pragma unroll
      for (int mi = 0; mi < 2; ++mi)
#pragma unroll
        for (int ni = 0; ni < 4; ++ni)
          acc[mi][ni] = __builtin_amdgcn_mfma_f32_16x16x32_f16(
              af[mi], bf[ni], acc[mi][ni], 0, 0, 0);
    }
    __syncthreads();
  }

#pragma unroll
  for (int ni = 0; ni < 4; ++ni) {
    const int c = n0 + ni * 16 + ln;
    const float bias_c = bo[c];
#pragma unroll
    for (int mi = 0; mi < 2; ++mi) {
      const int mb = m0 + w * 32 + mi * 16 + quad * 4;
#pragma unroll
      for (int r = 0; r < 4; ++r)
        out[(size_t)(mb + r) * DM + c] = acc[mi][ni][r] + bias_c;
    }
  }
}

// ---------------------------- flash attention ------------------------------
// R16: 2048 blocks x 4 waves, block = (bh = i&31, q-tile a = 63-(i>>5),
// longest first). Wave = (h = w>>1: q-half, e = w&1: kv parity), kv tiles
// t == e (mod 2) up to a. No K prefetch; K/V time-share kv[4] (disjoint
// lifetimes) -> ~64 unified regs -> target 8 blocks/CU (32 waves/CU).
// Ps: stride 64 halfs, slot = (rg + 2*ln) & 15 (conflict-free, R15).
// Parity merge via LDS: e==1 writes (O,l), one barrier, e==0 adds+outputs.

template <bool DIAG>
__device__ __forceinline__ void tile16(
    const _Float16* __restrict__ kb_, const _Float16* __restrict__ vb_,
    int t, const f16x8 (&qf)[2], f32x4 (&oacc)[4], float& l_i,
    _Float16* Ps, int quad, int ln, int l, int h)
{
  const f32x4 z4 = {0.f, 0.f, 0.f, 0.f};
  f16x8 kv[4];

  // K phase
#pragma unroll
  for (int ii = 0; ii < 4; ++ii)
    kv[ii] = *(const f16x8*)(kb_ + (size_t)(t * 4 + ii) * 512 + l * 8);

  f32x4 sacc[2];
  sacc[0] = z4; sacc[1] = z4;
#pragma unroll
  for (int ks = 0; ks < 2; ++ks)
#pragma unroll
    for (int mi = 0; mi < 2; ++mi)
      sacc[mi] = __builtin_amdgcn_mfma_f32_16x16x32_f16(
          kv[mi * 2 + ks], qf[ks], sacc[mi], 0, 0, 0);

  // V phase (reuses kv registers; latency hidden under exp2+LDS by TLP)
#pragma unroll
  for (int ii = 0; ii < 4; ++ii)
    kv[ii] = *(const f16x8*)(vb_ + (size_t)(t * 4 + ii) * 512 + l * 8);

  float rs = 0.f;
#pragma unroll
  for (int mi = 0; mi < 2; ++mi) {
    float p[4];
#pragma unroll
    for (int r = 0; r < 4; ++r) {
      p[r] = __builtin_amdgcn_exp2f(sacc[mi][r]);
      if (DIAG && (mi * 16 + quad * 4 + r > h * 16 + ln)) p[r] = 0.f;
      rs += p[r];
    }
    const f16x2 lo = pkrtz(p[0], p[1]);
    const f16x2 hi = pkrtz(p[2], p[3]);
    const f16x4 pk = __builtin_shufflevector(lo, hi, 0, 1, 2, 3);
    // slot swizzle: stride 64 halfs (128 B) -> row drops out of bank index.
    const int slot = ((mi * 4 + quad) + 2 * ln) & 15;
    *(f16x4*)&Ps[ln * 64 + slot * 4] = pk;
  }
  l_i += rs;

  const int slot2 = ((quad * 2) + 2 * ln) & 15;  // even -> 16B aligned
  const f16x8 pb = *(const f16x8*)&Ps[ln * 64 + slot2 * 4];

#pragma unroll
  for (int di = 0; di < 4; ++di)
    oacc[di] = __builtin_amdgcn_mfma_f32_16x16x32_f16(
        kv[di], pb, oacc[di], 0, 0, 0);
}

__global__ __launch_bounds__(256, 6) void attn_kernel(
    const _Float16* __restrict__ QF, const _Float16* __restrict__ KF,
    const _Float16* __restrict__ VF, _Float16* __restrict__ Ob)
{
  __shared__ _Float16 Ps[4 * 16 * 64];   // 8 KB (2 KB/wave)
  __shared__ float mrgO[2][1024];        // 8 KB: [pair][di*256 + l*4]
  __shared__ float mrgL[2][64];          // 512 B

  const int i = blockIdx.x;
  const int bh = i & 31;                 // all blocks of a head -> one XCD
  const int a = 63 - (i >> 5);           // q-tile; longest dispatched first

  const int tid = threadIdx.x;
  const int w = tid >> 6, l = tid & 63;
  const int quad = l >> 4, ln = l & 15;
  const int h = w >> 1;                  // q-half (pair id)
  const int e = w & 1;                   // kv parity

  const _Float16* qb_ = QF + (size_t)bh * 131072;
  const _Float16* kb_ = KF + (size_t)bh * 131072;
  const _Float16* vb_ = VF + (size_t)bh * 131072;
  _Float16* psw = Ps + w * (16 * 64);
  const int bidx = bh >> 4, hh = bh & 15;

  // Q fragments for rows [a*32 + h*16, +16)
  f16x8 qf[2];
#pragma unroll
  for (int ks = 0; ks < 2; ++ks)
    qf[ks] = *(const f16x8*)
        (qb_ + (size_t)((a * 2 + h) * 2 + ks) * 512 + l * 8);

  const f32x4 z4 = {0.f, 0.f, 0.f, 0.f};
  f32x4 oacc[4];
#pragma unroll
  for (int di = 0; di < 4; ++di) oacc[di] = z4;
  float l_i = 0.f;

  int t = e;
  for (; t < a; t += 2)
    tile16<false>(kb_, vb_, t, qf, oacc, l_i, psw, quad, ln, l, h);
  if (t == a)
    tile16<true>(kb_, vb_, t, qf, oacc, l_i, psw, quad, ln, l, h);

  // parity merge: e==1 writes, barrier, e==0 adds + outputs.
  if (e) {
#pragma unroll
    for (int di = 0; di < 4; ++di)
      *(f32x4*)&mrgO[h][di * 256 + l * 4] = oacc[di];
    mrgL[h][l] = l_i;
  }
  __syncthreads();
  if (!e) {
#pragma unroll
    for (int di = 0; di < 4; ++di)
      oacc[di] += *(const f32x4*)&mrgO[h][di * 256 + l * 4];
    l_i += mrgL[h][l];
    l_i += __shfl_xor(l_i, 16);
    l_i += __shfl_xor(l_i, 32);
    const float inv = 1.0f / l_i;

    const int q = a * 32 + h * 16 + ln;
    _Float16* orow = Ob + (size_t)(bidx * S_ + q) * DM + hh * DH + quad * 4;
#pragma unroll
    for (int di = 0; di < 4; ++di) {
      f16x4 o4;
#pragma unroll
      for (int r = 0; r < 4; ++r)
        o4[r] = (_Float16)(oacc[di][r] * inv);
      *(f16x4*)(orow + di * 16) = o4;
    }
  }
}

// ------------------------------- launcher ----------------------------------

extern "C" void kernel_launch(void* const* d_in, const int* in_sizes, int n_in,
                              void* d_out, int out_size, void* d_ws, size_t ws_size,
                              hipStream_t stream) {
  (void)in_sizes; (void)n_in; (void)out_size; (void)ws_size;
  const float* x  = (const float*)d_in[0];
  const float* Wq = (const float*)d_in[1];
  const float* bq = (const float*)d_in[2];
  const float* Wk = (const float*)d_in[3];
  const float* bk = (const float*)d_in[4];
  const float* Wv = (const float*)d_in[5];
  const float* bv = (const float*)d_in[6];
  const float* Wo = (const float*)d_in[7];
  const float* bo = (const float*)d_in[8];

  char* ws = (char*)d_ws;
  _Float16* xb  = (_Float16*)(ws);                      // 8 MB
  _Float16* wb  = (_Float16*)(ws + (8u << 20));         // 4 x 2 MB
  _Float16* qkv = (_Float16*)(ws + (16u << 20));        // QF,KF,VF 8 MB each
  _Float16* ob  = (_Float16*)(ws + (40u << 20));        // 8 MB

  cvt_all_kernel<<<dim3(8192), dim3(256), 0, stream>>>(x, Wq, Wk, Wv, Wo, xb, wb);
  gemm_qkv_kernel<<<dim3(8, 32, 3), dim3(256), 0, stream>>>(xb, wb, bq, bk, bv, qkv);
  attn_kernel<<<dim3(2048), dim3(256), 0, stream>>>(
      qkv, qkv + 4194304, qkv + 2 * 4194304, ob);
  gemm_out_kernel<<<dim3(16, 32), dim3(256), 0, stream>>>(
      ob, wb + (size_t)3 * DM * DM, bo, (float*)d_out);
}